// Round 7
// baseline (303.557 us; speedup 1.0000x reference)
//
#include <hip/hip_runtime.h>
#include <hip/hip_bf16.h>
#include <stdint.h>

// B=4, S=2048, D=1024, H=16, HD=64. Inputs fp32, OUTPUT fp32.
// Intermediates bf16. Workspace 64 MiB:
//   aws  [0, 16.8MB)   bf16 [B*S][D]   (wT1 overlays; dead before attn)
//   qkv  [16.8, 67.1MB) bf16 q|k|v each; V stored TRANSPOSED [B,H,HD,S] (R10)
//   wT2 overlays qws, written AFTER attn consumed Q.
// R13: hidden pre-converted to bf16 into d_out (dead until proj GEMM).
// R15: GEMMs ported to 256x128xBK64 triple-buffered counted-vmcnt kernel.
#define B_ 4
#define S_ 2048
#define D_ 1024
#define H_ 16
#define HD_ 64

typedef __bf16 bf16_t;
typedef bf16_t bf16x8 __attribute__((ext_vector_type(8)));
typedef bf16_t bf16x4 __attribute__((ext_vector_type(4)));
typedef float f32x4 __attribute__((ext_vector_type(4)));
typedef float f32x16 __attribute__((ext_vector_type(16)));

__device__ __forceinline__ bf16x8 cvt8(f32x4 lo, f32x4 hi) {
  bf16x8 r;
#pragma unroll
  for (int i = 0; i < 4; i++) {
    r[i] = (bf16_t)lo[i];
    r[i + 4] = (bf16_t)hi[i];
  }
  return r;
}

// Async global->LDS, 16B/lane; LDS dest = wave-uniform base + lane*16.
__device__ __forceinline__ void async_lds16(const bf16_t* g, bf16_t* l) {
  __builtin_amdgcn_global_load_lds(
      (const __attribute__((address_space(1))) void*)g,
      (__attribute__((address_space(3))) void*)l, 16, 0, 0);
}

// pack two f32 -> one u32 of two bf16 (elem0 = low 16 bits); compiler fuses.
__device__ __forceinline__ uint32_t pk2(float a, float b) {
  union {
    bf16_t h[2];
    uint32_t u;
  } x;
  x.h[0] = (bf16_t)a;
  x.h[1] = (bf16_t)b;
  return x.u;
}

// v_permlane32_swap_b32: a.hi_lanes <-> b.lo_lanes.
__device__ __forceinline__ void swap32(uint32_t& a, uint32_t& b) {
  asm("v_permlane32_swap_b32 %0, %1" : "+v"(a), "+v"(b));
}

union PAU {
  uint32_t w[4];
  bf16x8 v;
};

// ---------------------------------------------------------------------------
// fp32 -> bf16 bulk convert (R13). 8 elems/thread, vectorized.
// ---------------------------------------------------------------------------
__global__ __launch_bounds__(256) void cvt_f32_bf16(
    const float* __restrict__ in, bf16_t* __restrict__ out) {
  size_t i = ((size_t)blockIdx.x * 256 + threadIdx.x) * 8;
  f32x4 lo = *(const f32x4*)(in + i);
  f32x4 hi = *(const f32x4*)(in + i + 4);
  *(bf16x8*)(out + i) = cvt8(lo, hi);
}

// ---------------------------------------------------------------------------
// Weight cvt+transpose: in fp32 [R][C] -> out bf16 [C][R].
// ---------------------------------------------------------------------------
__global__ void transpose_cvt(const float* __restrict__ in,
                              bf16_t* __restrict__ out, int R, int C) {
  __shared__ bf16_t tile[32][33];
  int c0 = blockIdx.x * 32, r0 = blockIdx.y * 32;
  int tx = threadIdx.x, ty = threadIdx.y;  // 32 x 8
  for (int i = ty; i < 32; i += 8)
    tile[i][tx] = (bf16_t)in[(size_t)(r0 + i) * C + c0 + tx];
  __syncthreads();
  for (int i = ty; i < 32; i += 8)
    out[(size_t)(c0 + i) * R + r0 + tx] = tile[tx][i];
}

// ---------------------------------------------------------------------------
// GEMM R15: C[m,n] = sum_k A[m,k]*BT[n,k] + bias[n]. A,BT bf16 [rows][K].
// BM=256, BN=128, BK=64. 512 threads = 8 waves (2M x 4N); per-wave C 128x32
// (acc[8][2] f32x4). LDS: ring of 3 K-tile sets (A 32KB + B 16KB = 144KB).
// Schedule (T3/T4): iter j computes set j%3 (32 MFMA/wave) while K-tile j+2
// streams into set (j+2)%3 via global_load_lds w16. End of iter:
// lgkmcnt(0) -> vmcnt(6) (tile j+1's 6 loads are the oldest -> retired;
// tile j+2's may stay in flight; NEVER drains to 0) -> raw s_barrier.
// Set (j+2)%3 was freed at the barrier ending iter j-1 -> no overwrite race.
// T2: XOR slot-swizzle both-sides (pre-swizzled global src, swizzled
// ds_read_b128) -> 2-way LDS reads (free). T5: setprio around MFMA cluster.
// mode 0: fp32 store. mode 1: QKV scatter, V transposed [bb][H][HD][S].
// ---------------------------------------------------------------------------
__global__ __launch_bounds__(512, 2) void gemm256(
    const bf16_t* __restrict__ Ab, const bf16_t* __restrict__ Bb,
    const float* __restrict__ bias, float* __restrict__ Cout,
    bf16_t* __restrict__ qws, bf16_t* __restrict__ kws,
    bf16_t* __restrict__ vws, int M, int Nw, int K, int mode) {
  __shared__ bf16_t As[3 * 256 * 64];  // 96KB
  __shared__ bf16_t Bs[3 * 128 * 64];  // 48KB
  const int tid = threadIdx.x;
  const int wave = tid >> 6, lane = tid & 63;
  const int quad = lane >> 4, tn = lane & 15;
  const int m_blk = blockIdx.y * 256, n_blk = blockIdx.x * 128;
  const int wm = wave >> 2, wn = wave & 3;  // wave tile: rows wm*128, cols wn*32

  f32x4 acc[8][2] = {};

  // --- staging maps (pre-swizzled global source; linear LDS dest) ---------
  const int sr = tid >> 3;                 // row within a 64-row chunk
  const int asw = ((tid & 7) ^ (sr & 7)) * 8;  // swizzled 16B slot
  const bf16_t* aS[4];
  const bf16_t* bS[2];
#pragma unroll
  for (int c = 0; c < 4; c++)
    aS[c] = Ab + (size_t)(m_blk + c * 64 + sr) * K + asw;
#pragma unroll
  for (int c = 0; c < 2; c++)
    bS[c] = Bb + (size_t)(n_blk + c * 64 + sr) * K + asw;
  bf16_t* aD[4];
  bf16_t* bD[2];
#pragma unroll
  for (int c = 0; c < 4; c++) aD[c] = As + (size_t)(c * 512 + wave * 64) * 8;
#pragma unroll
  for (int c = 0; c < 2; c++) bD[c] = Bs + (size_t)(c * 512 + wave * 64) * 8;

#define GSTAGE(st, jt)                                              \
  do {                                                              \
    _Pragma("unroll") for (int c = 0; c < 4; c++)                   \
        async_lds16(aS[c] + (size_t)(jt) * 64, aD[c] + (st)*16384); \
    _Pragma("unroll") for (int c = 0; c < 2; c++)                   \
        async_lds16(bS[c] + (size_t)(jt) * 64, bD[c] + (st)*8192);  \
  } while (0)

  const int NT = K >> 6;  // K-tiles (>=2)

  // prologue: tiles 0,1 in flight; wait tile0 (allow tile1's 6 outstanding)
  GSTAGE(0, 0);
  GSTAGE(1, 1);
  asm volatile("s_waitcnt vmcnt(6)" ::: "memory");
  __builtin_amdgcn_s_barrier();
  __builtin_amdgcn_sched_barrier(0);

  int cur = 0;
  for (int j = 0; j < NT; ++j) {
    const int st2 = cur >= 1 ? cur - 1 : 2;  // (cur+2)%3
    if (j + 2 < NT) GSTAGE(st2, j + 2);

    const bf16_t* As_ = As + (size_t)cur * 16384;
    const bf16_t* Bs_ = Bs + (size_t)cur * 8192;
    __builtin_amdgcn_s_setprio(1);
#pragma unroll
    for (int ks = 0; ks < 2; ks++) {
      bf16x8 af[8], bfv[2];
#pragma unroll
      for (int mi = 0; mi < 8; mi++) {
        int row = wm * 128 + mi * 16 + tn;
        af[mi] = *(const bf16x8*)&As_[row * 64 +
                                      (((ks * 4 + quad) ^ (tn & 7)) * 8)];
      }
#pragma unroll
      for (int ni = 0; ni < 2; ni++) {
        int row = wn * 32 + ni * 16 + tn;
        bfv[ni] = *(const bf16x8*)&Bs_[row * 64 +
                                       (((ks * 4 + quad) ^ (tn & 7)) * 8)];
      }
#pragma unroll
      for (int mi = 0; mi < 8; mi++)
#pragma unroll
        for (int ni = 0; ni < 2; ni++)
          acc[mi][ni] = __builtin_amdgcn_mfma_f32_16x16x32_bf16(
              af[mi], bfv[ni], acc[mi][ni], 0, 0, 0);
    }
    __builtin_amdgcn_s_setprio(0);

    if (j + 1 < NT) {
      // my ds_reads retired (data in regs) before anyone restages this set
      asm volatile("s_waitcnt lgkmcnt(0)" ::: "memory");
      __builtin_amdgcn_sched_barrier(0);
      if (j + 2 < NT)
        asm volatile("s_waitcnt vmcnt(6)" ::: "memory");  // tile j+1 landed
      else
        asm volatile("s_waitcnt vmcnt(0)" ::: "memory");  // last tile landed
      __builtin_amdgcn_s_barrier();
      __builtin_amdgcn_sched_barrier(0);
    }
    cur = cur + 1 == 3 ? 0 : cur + 1;
  }
#undef GSTAGE

  // Epilogue. Frag C/D: col(n)=tn, row(m)=quad*4+r  [m89-verified]
  if (mode == 0) {  // fp32 final store
#pragma unroll
    for (int ni = 0; ni < 2; ni++) {
      int n = n_blk + wn * 32 + ni * 16 + tn;
      float bv = bias[n];
#pragma unroll
      for (int mi = 0; mi < 8; mi++)
#pragma unroll
        for (int r = 0; r < 4; r++) {
          int m = m_blk + wm * 128 + mi * 16 + quad * 4 + r;
          Cout[(size_t)m * Nw + n] = acc[mi][ni][r] + bv;
        }
    }
  } else {  // QKV scatter. sec block-uniform (n_blk multiple of 128).
#pragma unroll
    for (int ni = 0; ni < 2; ni++) {
      int n = n_blk + wn * 32 + ni * 16 + tn;
      int sec = n >> 10;
      int hn = n & 1023;
      int hh = hn >> 6, hd = hn & 63;
      float bv = bias[n];
      if (sec == 2) {  // V^T [bb][H][HD][S]: 4 consecutive s -> 8B store
#pragma unroll
        for (int mi = 0; mi < 8; mi++) {
          int m = m_blk + wm * 128 + mi * 16 + quad * 4;
          int bb = m >> 11, s = m & 2047;
          bf16x4 pk;
#pragma unroll
          for (int r = 0; r < 4; r++) pk[r] = (bf16_t)(acc[mi][ni][r] + bv);
          *(bf16x4*)&vws[((size_t)(bb * H_ + hh) * HD_ + hd) * S_ + s] = pk;
        }
      } else {
        bf16_t* dst = (sec == 0) ? qws : kws;
#pragma unroll
        for (int mi = 0; mi < 8; mi++)
#pragma unroll
          for (int r = 0; r < 4; r++) {
            int m = m_blk + wm * 128 + mi * 16 + quad * 4 + r;
            int bb = m >> 11, s = m & 2047;
            dst[((size_t)(bb * H_ + hh) * S_ + s) * HD_ + hd] =
                (bf16_t)(acc[mi][ni][r] + bv);
          }
      }
    }
  }
}

// ---------------------------------------------------------------------------
// Causal flash attention, R14 (unchanged): persistent-pair blocks.
// grid 256 = 1 block/CU; each block does two complementary q-tiles (36
// tile-units exactly). 8 waves, striped queries, swapped 32x32x16 QK^T,
// in-register P (pk2+permlane32_swap), row-sum via MFMA, K/V^T staged via
// global_load_lds w16 + slot-swizzle, double-buffer, 1 barrier/tile,
// T13 defer-max, setprio on MFMA clusters.
// ---------------------------------------------------------------------------
__global__ __launch_bounds__(512, 2) void attn_kernel(
    const bf16_t* __restrict__ Qw, const bf16_t* __restrict__ Kw,
    const bf16_t* __restrict__ VTw, bf16_t* __restrict__ Ow) {
  __shared__ bf16_t Ks[2][64 * 64];  // [key][hd], slot-swizzled
  __shared__ bf16_t Vt[2][64 * 64];  // [hd][key], slot-swizzled

  const int tid = threadIdx.x;
  const int wave = tid >> 6, lane = tid & 63;  // wave 0..7
  const int lq = lane & 31;   // query slot (and d-col) index within wave
  const int h = lane >> 5;    // half: k-subrange selector in A/B frags
  const int qoff = h * 4;     // C-layout row offset
  const int bid = blockIdx.x;          // 0..255
  const int j = bid >> 3;              // 0..31 within this XCD
  const int bh = (bid & 7) * 8 + (j >> 2);
  const int pj = j & 3;                // pair index 0..3

  const bf16_t* Qb = Qw + (size_t)bh * S_ * HD_;
  const bf16_t* Kb = Kw + (size_t)bh * S_ * HD_;
  const bf16_t* VTb = VTw + (size_t)bh * HD_ * S_;

  const float kScale = 0.125f * 1.44269504088896f;  // 1/sqrt(64) * log2(e)

  // ones B-frag for the row-sum MFMA
  bf16x8 onesf;
#pragma unroll
  for (int jj = 0; jj < 8; jj++) onesf[jj] = (bf16_t)1.0f;

  const float NEG = -30000.0f;
  const int b = bh >> 4, hh = bh & 15;

  // staging: per wave 2 async calls x 1KB (8 rows of 64 bf16 each).
  const int srow = wave * 8 + (lane >> 3);  // 0..63 across 8 waves
  const int sslot = lane & 7;
  const bf16_t* kp = Kb + (size_t)srow * HD_ + (sslot ^ (srow & 7)) * 8;
  const bf16_t* vp = VTb + (size_t)srow * S_ + (sslot ^ (srow & 7)) * 8;

#define STAGE(buf, kt)                                                 \
  do {                                                                 \
    async_lds16(kp + (size_t)(kt) * (64 * HD_), &Ks[buf][wave * 512]); \
    async_lds16(vp + (size_t)(kt) * 64, &Vt[buf][wave * 512]);         \
  } while (0)

  for (int task = 0; task < 2; task++) {
    const int qt = task == 0 ? (7 - pj) : pj;  // long first, then short
    const int qb = qt * 256;
    const int qa = qb + ((lq >> 3) << 6) + wave * 8 + (lq & 7);

    // Q B-frags: B[k][n=lq], k = h*8+j within each 16-wide slice kg.
    bf16x8 qf[4];
#pragma unroll
    for (int kg = 0; kg < 4; kg++) {
      bf16x8 v = *(const bf16x8*)&Qb[(size_t)qa * HD_ + kg * 16 + h * 8];
#pragma unroll
      for (int jj = 0; jj < 8; jj++) v[jj] = (bf16_t)((float)v[jj] * kScale);
      qf[kg] = v;
    }

    f32x16 o0 = {}, o1 = {};  // O[q-slot][d]: d = dblk*32+lq
    f32x16 ls = {};           // row-sum accumulator (same C-layout as o)
    float mrow = NEG;

    const int kt_max = (qb + 255) >> 6;  // inclusive; same for all waves

    if (task) __syncthreads();  // all waves done reading prev task's bufs
    STAGE(0, 0);

    for (int kt = 0; kt <= kt_max; kt++) {
      __syncthreads();  // drains vmcnt: buf[kt&1] staged; prev readers done
      if (kt < kt_max) STAGE((kt + 1) & 1, kt + 1);

      const bf16_t* KsB = Ks[kt & 1];
      const bf16_t* VtB = Vt[kt & 1];
      const int rsl = lq & 7;  // row-swizzle (same for lq and 32+lq)

      // QK^T swapped: st0 = keys 0..31 of tile, st1 = keys 32..63.
      f32x16 st0 = {}, st1 = {};
      __builtin_amdgcn_s_setprio(1);
#pragma unroll
      for (int kg = 0; kg < 4; kg++) {
        const int slot = kg * 2 + h;
        bf16x8 kf0 = *(const bf16x8*)&KsB[lq * 64 + ((slot ^ rsl) * 8)];
        bf16x8 kf1 = *(const bf16x8*)&KsB[(32 + lq) * 64 + ((slot ^ rsl) * 8)];
        st0 = __builtin_amdgcn_mfma_f32_32x32x16_bf16(kf0, qf[kg], st0, 0, 0, 0);
        st1 = __builtin_amdgcn_mfma_f32_32x32x16_bf16(kf1, qf[kg], st1, 0, 0, 0);
      }
      __builtin_amdgcn_s_setprio(0);
      // causal mask only on diagonal-region tiles. key(reg r) = kt*64 +
      // kblk*32 + (r&3) + 8*(r>>2) + 4h  [m74/m101 C-layout]
      if (kt * 64 + 63 > qb) {
#pragma unroll
        for (int r = 0; r < 16; r++) {
          int key0 = kt * 64 + (r & 3) + 8 * (r >> 2) + qoff;
          if (key0 > qa) st0[r] = NEG;
          if (key0 + 32 > qa) st1[r] = NEG;
        }
      }
      // row max: in-lane tree (31 fmax) + one cross-half exchange
      float m8[8];
#pragma unroll
      for (int i = 0; i < 4; i++) {
        m8[i] = fmaxf(fmaxf(st0[4 * i], st0[4 * i + 1]),
                      fmaxf(st0[4 * i + 2], st0[4 * i + 3]));
        m8[4 + i] = fmaxf(fmaxf(st1[4 * i], st1[4 * i + 1]),
                          fmaxf(st1[4 * i + 2], st1[4 * i + 3]));
      }
      float mx = fmaxf(fmaxf(fmaxf(m8[0], m8[1]), fmaxf(m8[2], m8[3])),
                       fmaxf(fmaxf(m8[4], m8[5]), fmaxf(m8[6], m8[7])));
      mx = fmaxf(mx, __shfl_xor(mx, 32, 64));

      // T13 defer-max: rescale only when max grew by > 8 (log2 domain)
      if (__any(mx > mrow + 8.f)) {
        float mnew = fmaxf(mrow, mx);
        float alpha = exp2f(mrow - mnew);
        mrow = mnew;
#pragma unroll
        for (int r = 0; r < 16; r++) {
          float ar = __shfl(alpha, (r & 3) + 8 * (r >> 2) + qoff, 64);
          o0[r] *= ar;
          o1[r] *= ar;
          ls[r] *= ar;
        }
      }
      // P = exp2(st - m) (bounded by 2^8 when deferred)
#pragma unroll
      for (int r = 0; r < 16; r++) {
        st0[r] = exp2f(st0[r] - mrow);
        st1[r] = exp2f(st1[r] - mrow);
      }

      // P -> PV A-frags, fully in-register: pack pairs, permlane32_swap.
      PAU pa[4];
      {
        uint32_t w[8];
#pragma unroll
        for (int i = 0; i < 8; i++) w[i] = pk2(st0[2 * i], st0[2 * i + 1]);
        swap32(w[0], w[2]);
        swap32(w[1], w[3]);
        swap32(w[4], w[6]);
        swap32(w[5], w[7]);
        pa[0].w[0] = w[0]; pa[0].w[1] = w[1]; pa[0].w[2] = w[2]; pa[0].w[3] = w[3];
        pa[1].w[0] = w[4]; pa[1].w[1] = w[5]; pa[1].w[2] = w[6]; pa[1].w[3] = w[7];
#pragma unroll
        for (int i = 0; i < 8; i++) w[i] = pk2(st1[2 * i], st1[2 * i + 1]);
        swap32(w[0], w[2]);
        swap32(w[1], w[3]);
        swap32(w[4], w[6]);
        swap32(w[5], w[7]);
        pa[2].w[0] = w[0]; pa[2].w[1] = w[1]; pa[2].w[2] = w[2]; pa[2].w[3] = w[3];
        pa[3].w[0] = w[4]; pa[3].w[1] = w[5]; pa[3].w[2] = w[6]; pa[3].w[3] = w[7];
      }

      // PV: O[q][d] += P*V; B-frag = Vt[d = dblk*32+lq][key kg*16+8h+j].
      __builtin_amdgcn_s_setprio(1);
#pragma unroll
      for (int kg = 0; kg < 4; kg++) {
        const int slot = kg * 2 + h;
        bf16x8 vf0 = *(const bf16x8*)&VtB[lq * 64 + ((slot ^ rsl) * 8)];
        bf16x8 vf1 = *(const bf16x8*)&VtB[(32 + lq) * 64 + ((slot ^ rsl) * 8)];
        o0 = __builtin_amdgcn_mfma_f32_32x32x16_bf16(pa[kg].v, vf0, o0, 0, 0, 0);
        o1 = __builtin_amdgcn_mfma_f32_32x32x16_bf16(pa[kg].v, vf1, o1, 0, 0, 0);
        ls = __builtin_amdgcn_mfma_f32_32x32x16_bf16(pa[kg].v, onesf, ls, 0, 0, 0);
      }
      __builtin_amdgcn_s_setprio(0);
    }

    // normalize + store merged heads [b][s][hh*64+d] (bf16). ls reg-local.
#pragma unroll
    for (int r = 0; r < 16; r++) {
      int qr = (r & 3) + 8 * (r >> 2) + qoff;  // q-slot of this C row
      int q = qb + ((qr >> 3) << 6) + wave * 8 + (qr & 7);  // striped remap
      float inv = 1.f / fmaxf(ls[r], 1e-30f);
      bf16_t* dst = Ow + (size_t)(b * S_ + q) * D_ + hh * HD_;
      dst[lq] = (bf16_t)(o0[r] * inv);
      dst[32 + lq] = (bf16_t)(o1[r] * inv);
    }
  }
#undef STAGE
}

// ---------------------------------------------------------------------------
extern "C" void kernel_launch(void* const* d_in, const int* in_sizes, int n_in,
                              void* d_out, int out_size, void* d_ws,
                              size_t ws_size, hipStream_t stream) {
  const float* hidden = nullptr;
  const float* attn_w = nullptr;
  const float* attn_b = nullptr;
  const float* proj_w = nullptr;
  const float* proj_b = nullptr;
  for (int i = 0; i < n_in; ++i) {
    switch (in_sizes[i]) {
      case 8388608: hidden = (const float*)d_in[i]; break;
      case 3145728: attn_w = (const float*)d_in[i]; break;
      case 3072:    attn_b = (const float*)d_in[i]; break;
      case 1048576: proj_w = (const float*)d_in[i]; break;
      case 1024:    proj_b = (const float*)d_in[i]; break;
      default: break;
    }
  }
  if (!hidden) hidden = (const float*)d_in[0];
  if (!attn_w) attn_w = (const float*)d_in[1];
  if (!attn_b) attn_b = (const float*)d_in[2];
  if (!proj_w) proj_w = (const float*)d_in[3];
  if (!proj_b) proj_b = (const float*)d_in[4];
  float* out = (float*)d_out;  // [4,2048,1024] fp32

  char* ws = (char*)d_ws;
  const size_t AWS_B = (size_t)B_ * S_ * D_ * 2;      // 16,777,216
  const size_t QKV_E = (size_t)B_ * H_ * S_ * HD_;    //  8,388,608 elems

  bf16_t* aws = (bf16_t*)ws;           // [B*S][D]
  bf16_t* wT1 = (bf16_t*)ws;           // [3072][1024] overlay (dead pre-attn)
  bf16_t* qws = (bf16_t*)(ws + AWS_B); // [B,H,S,HD]
  bf16_t* kws = qws + QKV_E;           // [B,H,S,HD]
  bf16_t* vws = kws + QKV_E;           // [B,H,HD,S]  (transposed, R10)
  bf16_t* wT2 = qws;                   // [1024][1024] overlay (post-attn)
  bf16_t* hb = (bf16_t*)d_out;         // hidden bf16 [8192][1024] overlay in
                                       // d_out (dead until proj GEMM, R13)

  // 0. hidden fp32 -> bf16 into d_out scratch (8.4M elems, 8/thread)
  cvt_f32_bf16<<<dim3(4096), 256, 0, stream>>>(hidden, hb);
  // 1. attn_w [1024][3072] -> wT1 bf16 [3072][1024]
  transpose_cvt<<<dim3(96, 32), dim3(32, 8), 0, stream>>>(attn_w, wT1, 1024, 3072);
  // 2. QKV GEMM (R15 256x128): hidden(bf16) x wT1 -> q/k + V^T scatter
  gemm256<<<dim3(24, 32), 512, 0, stream>>>(
      hb, wT1, attn_b, nullptr, qws, kws, vws, 8192, 3072, 1024, 1);
  // 3. attention -> aws (overwrites wT1: dead). 256 persistent-pair blocks.
  attn_kernel<<<dim3(256), 512, 0, stream>>>(qws, kws, vws, aws);
  // 4. proj_w [1024][1024] -> wT2 bf16 (overlays qws: dead after attn)
  transpose_cvt<<<dim3(32, 32), dim3(32, 8), 0, stream>>>(proj_w, wT2, 1024, 1024);
  // 5. proj GEMM (R15): aws(bf16) x wT2 -> out fp32 (overwrites hb scratch)
  gemm256<<<dim3(8, 32), 512, 0, stream>>>(
      aws, wT2, proj_b, out, nullptr, nullptr, nullptr, 8192, 1024, 1024, 0);
}

// Round 8
// 285.685 us; speedup vs baseline: 1.0626x; 1.0626x over previous
//
#include <hip/hip_runtime.h>
#include <hip/hip_bf16.h>
#include <stdint.h>

// B=4, S=2048, D=1024, H=16, HD=64. Inputs fp32, OUTPUT fp32.
// Intermediates bf16. Workspace 64 MiB (exact fit):
//   aws  [0, 16.8MB)   bf16 [B*S][D]   (wT1 overlays; dead before attn)
//   qkv  [16.8, 67.1MB) bf16 q|k|v each; V stored TRANSPOSED [B,H,HD,S] (R10)
//   wT2 overlays qws, written AFTER attn consumed Q.
// R13: hidden pre-converted to bf16 into d_out (dead until proj GEMM).
// R16: R15's gemm256 REVERTED (coarse phase-split = m196 regression; 1
// block/CU killed implicit multi-block overlap). gemm_bt restored + T1
// XCD-chunked block swizzle (each XCD owns 8 contiguous m-rows -> A panels
// L2-resident, B panels reused 8x per XCD).
#define B_ 4
#define S_ 2048
#define D_ 1024
#define H_ 16
#define HD_ 64

typedef __bf16 bf16_t;
typedef bf16_t bf16x8 __attribute__((ext_vector_type(8)));
typedef bf16_t bf16x4 __attribute__((ext_vector_type(4)));
typedef float f32x4 __attribute__((ext_vector_type(4)));
typedef float f32x16 __attribute__((ext_vector_type(16)));

__device__ __forceinline__ bf16x8 cvt8(f32x4 lo, f32x4 hi) {
  bf16x8 r;
#pragma unroll
  for (int i = 0; i < 4; i++) {
    r[i] = (bf16_t)lo[i];
    r[i + 4] = (bf16_t)hi[i];
  }
  return r;
}

// Async global->LDS, 16B/lane; LDS dest = wave-uniform base + lane*16.
__device__ __forceinline__ void async_lds16(const bf16_t* g, bf16_t* l) {
  __builtin_amdgcn_global_load_lds(
      (const __attribute__((address_space(1))) void*)g,
      (__attribute__((address_space(3))) void*)l, 16, 0, 0);
}

// pack two f32 -> one u32 of two bf16 (elem0 = low 16 bits); compiler fuses.
__device__ __forceinline__ uint32_t pk2(float a, float b) {
  union {
    bf16_t h[2];
    uint32_t u;
  } x;
  x.h[0] = (bf16_t)a;
  x.h[1] = (bf16_t)b;
  return x.u;
}

// v_permlane32_swap_b32: a.hi_lanes <-> b.lo_lanes.
__device__ __forceinline__ void swap32(uint32_t& a, uint32_t& b) {
  asm("v_permlane32_swap_b32 %0, %1" : "+v"(a), "+v"(b));
}

union PAU {
  uint32_t w[4];
  bf16x8 v;
};

// ---------------------------------------------------------------------------
// fp32 -> bf16 bulk convert (R13). 8 elems/thread, vectorized.
// ---------------------------------------------------------------------------
__global__ __launch_bounds__(256) void cvt_f32_bf16(
    const float* __restrict__ in, bf16_t* __restrict__ out) {
  size_t i = ((size_t)blockIdx.x * 256 + threadIdx.x) * 8;
  f32x4 lo = *(const f32x4*)(in + i);
  f32x4 hi = *(const f32x4*)(in + i + 4);
  *(bf16x8*)(out + i) = cvt8(lo, hi);
}

// ---------------------------------------------------------------------------
// Weight cvt+transpose: in fp32 [R][C] -> out bf16 [C][R].
// ---------------------------------------------------------------------------
__global__ void transpose_cvt(const float* __restrict__ in,
                              bf16_t* __restrict__ out, int R, int C) {
  __shared__ bf16_t tile[32][33];
  int c0 = blockIdx.x * 32, r0 = blockIdx.y * 32;
  int tx = threadIdx.x, ty = threadIdx.y;  // 32 x 8
  for (int i = ty; i < 32; i += 8)
    tile[i][tx] = (bf16_t)in[(size_t)(r0 + i) * C + c0 + tx];
  __syncthreads();
  for (int i = ty; i < 32; i += 8)
    out[(size_t)(c0 + i) * R + r0 + tx] = tile[tx][i];
}

// ---------------------------------------------------------------------------
// GEMM (m97 structure, R16 = R14 + XCD-chunked swizzle):
// C[m,n] = sum_k A[m,k]*BT[n,k] + bias[n].
// mode 0: fp32 store. mode 1: QKV scatter (bf16); V written TRANSPOSED
// [bb][H][HD][S] so attention can stage V^T via global_load_lds.
// ---------------------------------------------------------------------------
__global__ __launch_bounds__(256) void gemm_bt(
    const void* __restrict__ A, const bf16_t* __restrict__ BT,
    const float* __restrict__ bias, float* __restrict__ Cout,
    bf16_t* __restrict__ qws, bf16_t* __restrict__ kws,
    bf16_t* __restrict__ vws, int M, int Nw, int K, int mode, int a_is_f32,
    size_t a_off) {
  __shared__ bf16_t As[128 * 32];  // [m][k]
  __shared__ bf16_t Bs[128 * 32];  // [n][k]
  const int tid = threadIdx.x;
  const int wave = tid >> 6, lane = tid & 63;
  const int quad = lane >> 4, tn = lane & 15;
  // T1 XCD-chunked swizzle (bijective: nwg divisible by 8 for all our grids).
  // Dispatch round-robins linear id across 8 XCDs; remap so XCD x gets the
  // contiguous chunk [x*nwg/8, (x+1)*nwg/8): 8 m-rows x all n per XCD ->
  // A panels stay L2-resident, B panels reused 8x within the XCD.
  const int lid = blockIdx.y * gridDim.x + blockIdx.x;
  const int cpx = (gridDim.x * gridDim.y) >> 3;
  const int nl = (lid & 7) * cpx + (lid >> 3);
  const int m_blk = (nl / gridDim.x) * 128, n_blk = (nl % gridDim.x) * 128;
  const int wm = (wave >> 1) * 64, wn = (wave & 1) * 64;

  f32x4 acc[4][4] = {};

  const int srow = wave * 32 + (lane >> 2);
  const int scol = (lane & 3) * 8;
  size_t aoff = a_off + (size_t)(m_blk + srow) * K + scol;
  const bf16_t* gb = BT + (size_t)(n_blk + srow) * K + scol;
  bf16_t* lbB0 = &Bs[wave * 1024];
  bf16_t* lbB1 = &Bs[wave * 1024 + 512];
  bf16_t* laA0 = &As[wave * 1024];
  bf16_t* laA1 = &As[wave * 1024 + 512];

  for (int k0 = 0; k0 < K; k0 += 32) {
    async_lds16(gb, lbB0);
    async_lds16(gb + (size_t)16 * K, lbB1);
    if (a_is_f32) {
      const float* gaf = (const float*)A + aoff;
      f32x4 a00 = *(const f32x4*)gaf;
      f32x4 a01 = *(const f32x4*)(gaf + 4);
      f32x4 a10 = *(const f32x4*)(gaf + (size_t)16 * K);
      f32x4 a11 = *(const f32x4*)(gaf + (size_t)16 * K + 4);
      *(bf16x8*)&As[srow * 32 + scol] = cvt8(a00, a01);
      *(bf16x8*)&As[(srow + 16) * 32 + scol] = cvt8(a10, a11);
    } else {
      const bf16_t* ga = (const bf16_t*)A + aoff;
      async_lds16(ga, laA0);
      async_lds16(ga + (size_t)16 * K, laA1);
    }
    aoff += 32;
    gb += 32;
    __syncthreads();

    bf16x8 af[4], bfr[4];
#pragma unroll
    for (int i = 0; i < 4; i++)
      af[i] = *(const bf16x8*)&As[(wm + i * 16 + tn) * 32 + quad * 8];
#pragma unroll
    for (int i = 0; i < 4; i++)
      bfr[i] = *(const bf16x8*)&Bs[(wn + i * 16 + tn) * 32 + quad * 8];
#pragma unroll
    for (int mi = 0; mi < 4; mi++)
#pragma unroll
      for (int ni = 0; ni < 4; ni++)
        acc[mi][ni] = __builtin_amdgcn_mfma_f32_16x16x32_bf16(af[mi], bfr[ni],
                                                              acc[mi][ni], 0, 0, 0);
    __syncthreads();
  }

  // Epilogue. C/D: col(n)=lane&15, row(m)=quad*4+r  [m89-verified]
  if (mode == 0) {  // fp32 final store
#pragma unroll
    for (int ni = 0; ni < 4; ni++) {
      int n = n_blk + wn + ni * 16 + tn;
      float bv = bias[n];
#pragma unroll
      for (int mi = 0; mi < 4; mi++)
#pragma unroll
        for (int r = 0; r < 4; r++) {
          int m = m_blk + wm + mi * 16 + quad * 4 + r;
          Cout[(size_t)m * Nw + n] = acc[mi][ni][r] + bv;
        }
    }
  } else {  // QKV scatter. sec is block-uniform (n_blk multiple of 128).
#pragma unroll
    for (int ni = 0; ni < 4; ni++) {
      int n = n_blk + wn + ni * 16 + tn;
      int sec = n >> 10;
      int hn = n & 1023;
      int hh = hn >> 6, hd = hn & 63;
      float bv = bias[n];
      if (sec == 2) {  // V^T [bb][H][HD][S]: 4 consecutive s -> 8B store
#pragma unroll
        for (int mi = 0; mi < 4; mi++) {
          int m = m_blk + wm + mi * 16 + quad * 4;
          int bb = m >> 11, s = m & 2047;
          bf16x4 pk;
#pragma unroll
          for (int r = 0; r < 4; r++) pk[r] = (bf16_t)(acc[mi][ni][r] + bv);
          *(bf16x4*)&vws[((size_t)(bb * H_ + hh) * HD_ + hd) * S_ + s] = pk;
        }
      } else {
        bf16_t* dst = (sec == 0) ? qws : kws;
#pragma unroll
        for (int mi = 0; mi < 4; mi++)
#pragma unroll
          for (int r = 0; r < 4; r++) {
            int m = m_blk + wm + mi * 16 + quad * 4 + r;
            int bb = m >> 11, s = m & 2047;
            dst[((size_t)(bb * H_ + hh) * S_ + s) * HD_ + hd] =
                (bf16_t)(acc[mi][ni][r] + bv);
          }
      }
    }
  }
}

// ---------------------------------------------------------------------------
// Causal flash attention, R14 (unchanged): persistent-pair blocks.
// grid 256 = 1 block/CU; each block does two complementary q-tiles (36
// tile-units exactly). 8 waves, striped queries, swapped 32x32x16 QK^T,
// in-register P (pk2+permlane32_swap), row-sum via MFMA, K/V^T staged via
// global_load_lds w16 + slot-swizzle, double-buffer, 1 barrier/tile,
// T13 defer-max, setprio on MFMA clusters.
// ---------------------------------------------------------------------------
__global__ __launch_bounds__(512, 2) void attn_kernel(
    const bf16_t* __restrict__ Qw, const bf16_t* __restrict__ Kw,
    const bf16_t* __restrict__ VTw, bf16_t* __restrict__ Ow) {
  __shared__ bf16_t Ks[2][64 * 64];  // [key][hd], slot-swizzled
  __shared__ bf16_t Vt[2][64 * 64];  // [hd][key], slot-swizzled

  const int tid = threadIdx.x;
  const int wave = tid >> 6, lane = tid & 63;  // wave 0..7
  const int lq = lane & 31;   // query slot (and d-col) index within wave
  const int h = lane >> 5;    // half: k-subrange selector in A/B frags
  const int qoff = h * 4;     // C-layout row offset
  const int bid = blockIdx.x;          // 0..255
  const int j = bid >> 3;              // 0..31 within this XCD
  const int bh = (bid & 7) * 8 + (j >> 2);
  const int pj = j & 3;                // pair index 0..3

  const bf16_t* Qb = Qw + (size_t)bh * S_ * HD_;
  const bf16_t* Kb = Kw + (size_t)bh * S_ * HD_;
  const bf16_t* VTb = VTw + (size_t)bh * HD_ * S_;

  const float kScale = 0.125f * 1.44269504088896f;  // 1/sqrt(64) * log2(e)

  // ones B-frag for the row-sum MFMA
  bf16x8 onesf;
#pragma unroll
  for (int jj = 0; jj < 8; jj++) onesf[jj] = (bf16_t)1.0f;

  const float NEG = -30000.0f;
  const int b = bh >> 4, hh = bh & 15;

  // staging: per wave 2 async calls x 1KB (8 rows of 64 bf16 each).
  const int srow = wave * 8 + (lane >> 3);  // 0..63 across 8 waves
  const int sslot = lane & 7;
  const bf16_t* kp = Kb + (size_t)srow * HD_ + (sslot ^ (srow & 7)) * 8;
  const bf16_t* vp = VTb + (size_t)srow * S_ + (sslot ^ (srow & 7)) * 8;

#define STAGE(buf, kt)                                                 \
  do {                                                                 \
    async_lds16(kp + (size_t)(kt) * (64 * HD_), &Ks[buf][wave * 512]); \
    async_lds16(vp + (size_t)(kt) * 64, &Vt[buf][wave * 512]);         \
  } while (0)

  for (int task = 0; task < 2; task++) {
    const int qt = task == 0 ? (7 - pj) : pj;  // long first, then short
    const int qb = qt * 256;
    const int qa = qb + ((lq >> 3) << 6) + wave * 8 + (lq & 7);

    // Q B-frags: B[k][n=lq], k = h*8+j within each 16-wide slice kg.
    bf16x8 qf[4];
#pragma unroll
    for (int kg = 0; kg < 4; kg++) {
      bf16x8 v = *(const bf16x8*)&Qb[(size_t)qa * HD_ + kg * 16 + h * 8];
#pragma unroll
      for (int jj = 0; jj < 8; jj++) v[jj] = (bf16_t)((float)v[jj] * kScale);
      qf[kg] = v;
    }

    f32x16 o0 = {}, o1 = {};  // O[q-slot][d]: d = dblk*32+lq
    f32x16 ls = {};           // row-sum accumulator (same C-layout as o)
    float mrow = NEG;

    const int kt_max = (qb + 255) >> 6;  // inclusive; same for all waves

    if (task) __syncthreads();  // all waves done reading prev task's bufs
    STAGE(0, 0);

    for (int kt = 0; kt <= kt_max; kt++) {
      __syncthreads();  // drains vmcnt: buf[kt&1] staged; prev readers done
      if (kt < kt_max) STAGE((kt + 1) & 1, kt + 1);

      const bf16_t* KsB = Ks[kt & 1];
      const bf16_t* VtB = Vt[kt & 1];
      const int rsl = lq & 7;  // row-swizzle (same for lq and 32+lq)

      // QK^T swapped: st0 = keys 0..31 of tile, st1 = keys 32..63.
      f32x16 st0 = {}, st1 = {};
      __builtin_amdgcn_s_setprio(1);
#pragma unroll
      for (int kg = 0; kg < 4; kg++) {
        const int slot = kg * 2 + h;
        bf16x8 kf0 = *(const bf16x8*)&KsB[lq * 64 + ((slot ^ rsl) * 8)];
        bf16x8 kf1 = *(const bf16x8*)&KsB[(32 + lq) * 64 + ((slot ^ rsl) * 8)];
        st0 = __builtin_amdgcn_mfma_f32_32x32x16_bf16(kf0, qf[kg], st0, 0, 0, 0);
        st1 = __builtin_amdgcn_mfma_f32_32x32x16_bf16(kf1, qf[kg], st1, 0, 0, 0);
      }
      __builtin_amdgcn_s_setprio(0);
      // causal mask only on diagonal-region tiles. key(reg r) = kt*64 +
      // kblk*32 + (r&3) + 8*(r>>2) + 4h  [m74/m101 C-layout]
      if (kt * 64 + 63 > qb) {
#pragma unroll
        for (int r = 0; r < 16; r++) {
          int key0 = kt * 64 + (r & 3) + 8 * (r >> 2) + qoff;
          if (key0 > qa) st0[r] = NEG;
          if (key0 + 32 > qa) st1[r] = NEG;
        }
      }
      // row max: in-lane tree (31 fmax) + one cross-half exchange
      float m8[8];
#pragma unroll
      for (int i = 0; i < 4; i++) {
        m8[i] = fmaxf(fmaxf(st0[4 * i], st0[4 * i + 1]),
                      fmaxf(st0[4 * i + 2], st0[4 * i + 3]));
        m8[4 + i] = fmaxf(fmaxf(st1[4 * i], st1[4 * i + 1]),
                          fmaxf(st1[4 * i + 2], st1[4 * i + 3]));
      }
      float mx = fmaxf(fmaxf(fmaxf(m8[0], m8[1]), fmaxf(m8[2], m8[3])),
                       fmaxf(fmaxf(m8[4], m8[5]), fmaxf(m8[6], m8[7])));
      mx = fmaxf(mx, __shfl_xor(mx, 32, 64));

      // T13 defer-max: rescale only when max grew by > 8 (log2 domain)
      if (__any(mx > mrow + 8.f)) {
        float mnew = fmaxf(mrow, mx);
        float alpha = exp2f(mrow - mnew);
        mrow = mnew;
#pragma unroll
        for (int r = 0; r < 16; r++) {
          float ar = __shfl(alpha, (r & 3) + 8 * (r >> 2) + qoff, 64);
          o0[r] *= ar;
          o1[r] *= ar;
          ls[r] *= ar;
        }
      }
      // P = exp2(st - m) (bounded by 2^8 when deferred)
#pragma unroll
      for (int r = 0; r < 16; r++) {
        st0[r] = exp2f(st0[r] - mrow);
        st1[r] = exp2f(st1[r] - mrow);
      }

      // P -> PV A-frags, fully in-register: pack pairs, permlane32_swap.
      PAU pa[4];
      {
        uint32_t w[8];
#pragma unroll
        for (int i = 0; i < 8; i++) w[i] = pk2(st0[2 * i], st0[2 * i + 1]);
        swap32(w[0], w[2]);
        swap32(w[1], w[3]);
        swap32(w[4], w[6]);
        swap32(w[5], w[7]);
        pa[0].w[0] = w[0]; pa[0].w[1] = w[1]; pa[0].w[2] = w[2]; pa[0].w[3] = w[3];
        pa[1].w[0] = w[4]; pa[1].w[1] = w[5]; pa[1].w[2] = w[6]; pa[1].w[3] = w[7];
#pragma unroll
        for (int i = 0; i < 8; i++) w[i] = pk2(st1[2 * i], st1[2 * i + 1]);
        swap32(w[0], w[2]);
        swap32(w[1], w[3]);
        swap32(w[4], w[6]);
        swap32(w[5], w[7]);
        pa[2].w[0] = w[0]; pa[2].w[1] = w[1]; pa[2].w[2] = w[2]; pa[2].w[3] = w[3];
        pa[3].w[0] = w[4]; pa[3].w[1] = w[5]; pa[3].w[2] = w[6]; pa[3].w[3] = w[7];
      }

      // PV: O[q][d] += P*V; B-frag = Vt[d = dblk*32+lq][key kg*16+8h+j].
      __builtin_amdgcn_s_setprio(1);
#pragma unroll
      for (int kg = 0; kg < 4; kg++) {
        const int slot = kg * 2 + h;
        bf16x8 vf0 = *(const bf16x8*)&VtB[lq * 64 + ((slot ^ rsl) * 8)];
        bf16x8 vf1 = *(const bf16x8*)&VtB[(32 + lq) * 64 + ((slot ^ rsl) * 8)];
        o0 = __builtin_amdgcn_mfma_f32_32x32x16_bf16(pa[kg].v, vf0, o0, 0, 0, 0);
        o1 = __builtin_amdgcn_mfma_f32_32x32x16_bf16(pa[kg].v, vf1, o1, 0, 0, 0);
        ls = __builtin_amdgcn_mfma_f32_32x32x16_bf16(pa[kg].v, onesf, ls, 0, 0, 0);
      }
      __builtin_amdgcn_s_setprio(0);
    }

    // normalize + store merged heads [b][s][hh*64+d] (bf16). ls reg-local.
#pragma unroll
    for (int r = 0; r < 16; r++) {
      int qr = (r & 3) + 8 * (r >> 2) + qoff;  // q-slot of this C row
      int q = qb + ((qr >> 3) << 6) + wave * 8 + (qr & 7);  // striped remap
      float inv = 1.f / fmaxf(ls[r], 1e-30f);
      bf16_t* dst = Ow + (size_t)(b * S_ + q) * D_ + hh * HD_;
      dst[lq] = (bf16_t)(o0[r] * inv);
      dst[32 + lq] = (bf16_t)(o1[r] * inv);
    }
  }
#undef STAGE
}

// ---------------------------------------------------------------------------
extern "C" void kernel_launch(void* const* d_in, const int* in_sizes, int n_in,
                              void* d_out, int out_size, void* d_ws,
                              size_t ws_size, hipStream_t stream) {
  const float* hidden = nullptr;
  const float* attn_w = nullptr;
  const float* attn_b = nullptr;
  const float* proj_w = nullptr;
  const float* proj_b = nullptr;
  for (int i = 0; i < n_in; ++i) {
    switch (in_sizes[i]) {
      case 8388608: hidden = (const float*)d_in[i]; break;
      case 3145728: attn_w = (const float*)d_in[i]; break;
      case 3072:    attn_b = (const float*)d_in[i]; break;
      case 1048576: proj_w = (const float*)d_in[i]; break;
      case 1024:    proj_b = (const float*)d_in[i]; break;
      default: break;
    }
  }
  if (!hidden) hidden = (const float*)d_in[0];
  if (!attn_w) attn_w = (const float*)d_in[1];
  if (!attn_b) attn_b = (const float*)d_in[2];
  if (!proj_w) proj_w = (const float*)d_in[3];
  if (!proj_b) proj_b = (const float*)d_in[4];
  float* out = (float*)d_out;  // [4,2048,1024] fp32

  char* ws = (char*)d_ws;
  const size_t AWS_B = (size_t)B_ * S_ * D_ * 2;      // 16,777,216
  const size_t QKV_E = (size_t)B_ * H_ * S_ * HD_;    //  8,388,608 elems

  bf16_t* aws = (bf16_t*)ws;           // [B*S][D]
  bf16_t* wT1 = (bf16_t*)ws;           // [3072][1024] overlay (dead pre-attn)
  bf16_t* qws = (bf16_t*)(ws + AWS_B); // [B,H,S,HD]
  bf16_t* kws = qws + QKV_E;           // [B,H,S,HD]
  bf16_t* vws = kws + QKV_E;           // [B,H,HD,S]  (transposed, R10)
  bf16_t* wT2 = qws;                   // [1024][1024] overlay (post-attn)
  bf16_t* hb = (bf16_t*)d_out;         // hidden bf16 [8192][1024] overlay in
                                       // d_out (dead until proj GEMM, R13)

  // 0. hidden fp32 -> bf16 into d_out scratch (8.4M elems, 8/thread)
  cvt_f32_bf16<<<dim3(4096), 256, 0, stream>>>(hidden, hb);
  // 1. attn_w [1024][3072] -> wT1 bf16 [3072][1024]
  transpose_cvt<<<dim3(96, 32), dim3(32, 8), 0, stream>>>(attn_w, wT1, 1024, 3072);
  // 2. QKV GEMM: hidden(bf16, async-A staging) x wT1 -> q/k + V^T scatter
  gemm_bt<<<dim3(24, 64), 256, 0, stream>>>(
      hb, wT1, attn_b, nullptr, qws, kws, vws, 8192, 3072, 1024, 1, 0, 0);
  // 3. attention -> aws (overwrites wT1: dead). 256 persistent-pair blocks.
  attn_kernel<<<dim3(256), 512, 0, stream>>>(qws, kws, vws, aws);
  // 4. proj_w [1024][1024] -> wT2 bf16 (overlays qws: dead after attn)
  transpose_cvt<<<dim3(32, 32), dim3(32, 8), 0, stream>>>(proj_w, wT2, 1024, 1024);
  // 5. proj GEMM: aws(bf16) x wT2 -> out fp32 (overwrites hb scratch)
  gemm_bt<<<dim3(8, 64), 256, 0, stream>>>(
      aws, wT2, proj_b, out, nullptr, nullptr, nullptr, 8192, 1024, 1024, 0, 0, 0);
}